// Round 7
// baseline (278.139 us; speedup 1.0000x reference)
//
#include <hip/hip_runtime.h>
#include <hip/hip_bf16.h>
#include <math.h>

// DotProductAttention: B=16, Q=2048, K=2048, D=128, fp32 in/out.
// Query-axis masking: rows q >= valid_lens[b] -> uniform softmax -> mean(V)
// (combine writes those rows exactly from fp32 V column sums).
//
// Round 7: R5 flash structure (32 q/wave, VGPR=128, no spills — R6's 64 q/wave
// spilled to scratch: WRITE 146MB) but KT=64: 32KB LDS/block -> 4 blocks/CU
// (was 2) for 2x latency hiding. 32x32x16 MFMA S^T slot-permutation layout
// (verified R5): pi = swap bits 2<->3; S^T C-regs ARE the PV A-fragment.
// Vt stored as 16KB 64-key tiles [b][k/64][d][k%64], 3-bit XOR granule swizzle.
//
// ws: [0,8K) sumV | Kh 8M (swizzled granules) | Vt 8M (64-key tiles, swizzled)
//     | Po f16 SEG planes | Lb f32.  SEG=8 needs 84.94MB (proven <= ws R5).

#define Bn 16
#define Qn 2048
#define Kn 2048
#define Dn 128
#define SCALE 0.08838834764831845f  // 1/sqrt(128)

typedef _Float16 f16;
typedef _Float16 f16x8_t __attribute__((ext_vector_type(8)));
typedef float f32x16_t __attribute__((ext_vector_type(16)));

typedef __attribute__((address_space(1))) const unsigned int glb_u32;
typedef __attribute__((address_space(3))) unsigned int lds_u32;

__device__ __forceinline__ void g2l16(const void* g, void* l) {
  __builtin_amdgcn_global_load_lds((glb_u32*)g, (lds_u32*)l, 16, 0, 0);
}

// ---------------- prep: K->f16 swizzled granules, V->Vt 64-key tiles, colsum
// grid (32, 4, 16) block (32,8).
// Kh key-row k (256B): granule G=d>>3 stored at slot (G&8)|((G&7)^(k&7)).
// Vt tile [b][kb=k/64][d][kk=k%64] (16KB): granule G=kk>>3 (0..7) at slot
// G^(d&7), i.e. element addr ((b*32+kb)*128+d)*64 + slot*8 + (kk&7).

__global__ void __launch_bounds__(256) prep_kernel(
    const float* __restrict__ Kg, const float* __restrict__ Vg,
    f16* __restrict__ Kh, f16* __restrict__ Vt, float* __restrict__ sv) {
  __shared__ float ps[8][32];
  const int b = blockIdx.z;
  const int x = threadIdx.x, y = threadIdx.y;

  // K: 16 key-rows per block, one granule (8 d) per thread, 16B store
  {
    const int lb = (b * 4 + blockIdx.y) * 32 + blockIdx.x;  // 0..2047
    const int t = y * 32 + x;
    const size_t key = (size_t)lb * 16 + (t >> 4);  // global (b*2048+k)
    const int G = t & 15;
    const float* kp = Kg + (key << 7) + G * 8;
    float4 f0 = *(const float4*)kp;
    float4 f1 = *(const float4*)(kp + 4);
    f16x8_t o;
    o[0] = (f16)f0.x; o[1] = (f16)f0.y; o[2] = (f16)f0.z; o[3] = (f16)f0.w;
    o[4] = (f16)f1.x; o[5] = (f16)f1.y; o[6] = (f16)f1.z; o[7] = (f16)f1.w;
    const int gs = (G & 8) | ((G & 7) ^ ((int)key & 7));
    *(f16x8_t*)(Kh + (key << 7) + (gs << 3)) = o;
  }

  // V: 64 keys x 32 d per block; thread owns one Vt granule in-register
  const int k0 = blockIdx.x * 64, d0 = blockIdx.y * 32;
  const int d = d0 + x;
  const float* vp = Vg + ((size_t)b * Kn + k0 + y * 8) * Dn + d;
  float s = 0.f;
  f16x8_t gr;
#pragma unroll
  for (int j = 0; j < 8; j++) {
    float v = vp[(size_t)j * Dn];
    s += v;
    gr[j] = (f16)v;
  }
  {
    const int kb = k0 >> 6;            // 64-key tile index
    const int G = y;                   // kk granule 0..7
    const int gs = G ^ (d & 7);
    *(f16x8_t*)(Vt + (((size_t)(b * (Kn / 64) + kb) * 128 + d) << 6) + (gs << 3)) = gr;
  }

  // column sums for the masked fast path
  ps[y][x] = s;
  __syncthreads();
  if (y == 0) {
    float tot = 0.f;
#pragma unroll
    for (int j = 0; j < 8; j++) tot += ps[j][x];
    atomicAdd(&sv[b * Dn + d0 + x], tot);
  }
}

// valid_lens may be stored as int32 or int64. Sniff: odd words all zero -> 64.
__device__ __forceinline__ int load_vl(const int* __restrict__ vlp, int b) {
  bool is64 = true;
#pragma unroll
  for (int i = 1; i < 16; i += 2) is64 = is64 && (vlp[i] == 0);
  return is64 ? vlp[2 * b] : vlp[b];
}

// ---------------- flash: 32x32 MFMA, 32 q/wave, 64-key tiles, 4 blocks/CU ---
// grid (16, 16, S) block 256

template <int S>
__global__ void __launch_bounds__(256, 4) flash_kernel(
    const float* __restrict__ Qg, const f16* __restrict__ Kh,
    const f16* __restrict__ Vt, const int* __restrict__ vlp,
    f16* __restrict__ Po, float* __restrict__ Lb) {
  const int b = blockIdx.y;
  const int seg = blockIdx.z;
  const int qt = (blockIdx.x * 5 + seg * 3) & 15;  // scatter active tiles
  const int q0 = qt * 128;
  const int vl = load_vl(vlp, b);
  if (q0 >= vl) return;  // uniform per block, before any barrier

  __shared__ __align__(16) f16 Ks[64 * 128];  // 16 KB: 64 keys x 256B rows
  __shared__ __align__(16) f16 Vs[128 * 64];  // 16 KB: 128 d   x 128B rows

  const int tid = threadIdx.x;
  const int wave = tid >> 6, lane = tid & 63;
  const int H = lane >> 5, l5 = lane & 31;
  const int qbase = q0 + wave * 32;
  const bool act = qbase < vl;
  const int q_lane = qbase + l5;
  const float sc = (q_lane >= vl) ? 0.f : SCALE;  // masked row: p=1 -> uniform

  // pi = swap bits 2<->3: A-row slot l5 holds physical key pi(l5) [R5-verified]
  const int krow = (l5 & 0x13) | ((l5 & 4) << 1) | ((l5 & 8) >> 1);
  const int krow7 = krow & 7;

  // Q fragments (B-operand of S^T): lane = q-col l5, k-els d = 16s+8H+j
  f16x8_t qf[8];
  if (act) {
    const float* qp = Qg + ((size_t)b * Qn + q_lane) * Dn + 8 * H;
#pragma unroll
    for (int s = 0; s < 8; s++) {
      float4 f0 = *(const float4*)(qp + 16 * s);
      float4 f1 = *(const float4*)(qp + 16 * s + 4);
      f16x8_t q8;
      q8[0] = (f16)f0.x; q8[1] = (f16)f0.y; q8[2] = (f16)f0.z; q8[3] = (f16)f0.w;
      q8[4] = (f16)f1.x; q8[5] = (f16)f1.y; q8[6] = (f16)f1.z; q8[7] = (f16)f1.w;
      qf[s] = q8;
    }
  }

  f32x16_t O[4];
#pragma unroll
  for (int i = 0; i < 4; i++) O[i] = (f32x16_t)(0.f);
  float l_lane = 0.f;

  const char* KgT = (const char*)Kh + (((size_t)b * Kn + (size_t)seg * (Kn / S)) << 8);
  const char* VgT = (const char*)Vt + ((size_t)(b * (Kn / 64) + seg * (Kn / S) / 64) << 14);

  for (int it = 0; it < (Kn / S) / 64; it++) {
    __syncthreads();  // protect LDS from previous iter's readers
    // stage 32 KB: 8 x 1KB chunks per wave (4 K + 4 V), width-16 DMA
    const char* kg = KgT + (size_t)it * 16384 + wave * 4096 + lane * 16;
    const char* vg = VgT + (size_t)it * 16384 + wave * 4096 + lane * 16;
    f16* kl = Ks + wave * 2048;
    f16* vli = Vs + wave * 2048;
#pragma unroll
    for (int i = 0; i < 4; i++) {
      g2l16(kg + i * 1024, kl + i * 512);
      g2l16(vg + i * 1024, vli + i * 512);
    }
    __syncthreads();

    if (act) {
#pragma unroll
      for (int sub = 0; sub < 2; sub++) {
        // S^T = K.Q^T over keys sub*32..+31
        f32x16_t T = (f32x16_t)(0.f);
        const f16* krp = Ks + ((sub * 32 + krow) << 7);
#pragma unroll
        for (int s = 0; s < 8; s++) {
          const int G = 2 * s + H;
          const int gs = (G & 8) | ((G & 7) ^ krow7);
          f16x8_t kf = *(const f16x8_t*)(krp + (gs << 3));
          T = __builtin_amdgcn_mfma_f32_32x32x16_f16(kf, qf[s], T, 0, 0, 0);
        }

        // p = exp(s); C-regs are the PV A-fragment (key 16(r>>3)+8H+(r&7))
        f16x8_t pf0, pf1;
        float ls = 0.f;
#pragma unroll
        for (int r = 0; r < 8; r++) {
          float p = __expf(T[r] * sc);
          ls += p;
          pf0[r] = (f16)p;
        }
#pragma unroll
        for (int r = 8; r < 16; r++) {
          float p = __expf(T[r] * sc);
          ls += p;
          pf1[r - 8] = (f16)p;
        }
        l_lane += ls;

        // O += P.V : B-frags from swizzled Vs (d-row dt*32+l5, 128B rows)
#pragma unroll
        for (int dt = 0; dt < 4; dt++) {
          const f16* vrp = Vs + ((dt * 32 + l5) << 6);
          const int G0 = sub * 4 + H, G1 = sub * 4 + 2 + H;  // 0..7
          const int gs0 = G0 ^ (l5 & 7);
          const int gs1 = G1 ^ (l5 & 7);
          f16x8_t vf0 = *(const f16x8_t*)(vrp + (gs0 << 3));
          f16x8_t vf1 = *(const f16x8_t*)(vrp + (gs1 << 3));
          O[dt] = __builtin_amdgcn_mfma_f32_32x32x16_f16(pf0, vf0, O[dt], 0, 0, 0);
          O[dt] = __builtin_amdgcn_mfma_f32_32x32x16_f16(pf1, vf1, O[dt], 0, 0, 0);
        }
      }
    }
  }

  if (!act) return;

  // epilogue: unnormalized partials
  l_lane += __shfl_xor(l_lane, 32);
  if (lane < 32) Lb[(size_t)(seg * Bn + b) * Qn + qbase + l5] = l_lane;

  f16* po = Po + ((size_t)(seg * Bn + b) * Qn + qbase) * Dn;
#pragma unroll
  for (int dt = 0; dt < 4; dt++) {
#pragma unroll
    for (int r = 0; r < 16; r++) {
      const int qrow = (r & 3) + 8 * (r >> 2) + 4 * H;  // PV C-layout row
      po[(size_t)qrow * Dn + dt * 32 + l5] = (f16)O[dt][r];
    }
  }
}

// ---------------- combine: out = sum_s O_s / sum_s l_s; masked rows = mean(V)
// grid (32, 16) block 256; 64 q-rows per block, 8 d per thread.

template <int S>
__global__ void __launch_bounds__(256) combine_kernel(
    const f16* __restrict__ Po, const float* __restrict__ Lb,
    const float* __restrict__ sv, const int* __restrict__ vlp,
    float* __restrict__ Out) {
  const int b = blockIdx.y, q0 = blockIdx.x * 64;
  const int vl = load_vl(vlp, b);
  const int tid = threadIdx.x;

  __shared__ float linv[64];
  if (tid < 64) {
    float s = 0.f;
#pragma unroll
    for (int sg = 0; sg < S; sg++) s += Lb[(size_t)(sg * Bn + b) * Qn + q0 + tid];
    linv[tid] = 1.0f / s;
  }
  __syncthreads();

  const int row16 = tid >> 4;      // 0..15
  const int d8 = (tid & 15) * 8;   // 0..120
  const float invK = 1.0f / (float)Kn;
  float mv[8];
#pragma unroll
  for (int j = 0; j < 8; j++) mv[j] = sv[b * Dn + d8 + j] * invK;

#pragma unroll
  for (int pass = 0; pass < 4; pass++) {
    const int row = pass * 16 + row16;
    const int q = q0 + row;
    float acc[8];
    if (q >= vl) {
#pragma unroll
      for (int j = 0; j < 8; j++) acc[j] = mv[j];  // fp32-exact uniform result
    } else {
#pragma unroll
      for (int j = 0; j < 8; j++) acc[j] = 0.f;
#pragma unroll
      for (int sg = 0; sg < S; sg++) {
        f16x8_t v = *(const f16x8_t*)(Po + ((size_t)(sg * Bn + b) * Qn + q) * Dn + d8);
#pragma unroll
        for (int j = 0; j < 8; j++) acc[j] += (float)v[j];
      }
      const float li = linv[row];
#pragma unroll
      for (int j = 0; j < 8; j++) acc[j] *= li;
    }
    float4 o0 = make_float4(acc[0], acc[1], acc[2], acc[3]);
    float4 o1 = make_float4(acc[4], acc[5], acc[6], acc[7]);
    float* op = Out + ((size_t)b * Qn + q) * Dn + d8;
    *(float4*)op = o0;
    *(float4*)(op + 4) = o1;
  }
}

// ---------------- launch ----------------

extern "C" void kernel_launch(void* const* d_in, const int* in_sizes, int n_in,
                              void* d_out, int out_size, void* d_ws, size_t ws_size,
                              hipStream_t stream) {
  const float* Qg = (const float*)d_in[0];
  const float* Kg = (const float*)d_in[1];
  const float* Vg = (const float*)d_in[2];
  const int* vl = (const int*)d_in[3];
  float* Out = (float*)d_out;

  char* ws = (char*)d_ws;
  float* sumV = (float*)ws;                                // 8 KB
  f16* Kh = (f16*)(ws + 8192);                             // 8 MB
  f16* Vt = (f16*)(ws + 8192 + (size_t)Bn * Kn * Dn * 2);  // 8 MB
  const size_t base = 8192 + 2 * (size_t)Bn * Kn * Dn * 2;
  f16* Po = (f16*)(ws + base);

  const size_t po8 = (size_t)8 * Bn * Qn * Dn * 2;  // 67.1 MB
  const size_t lb8 = (size_t)8 * Bn * Qn * 4;       // 1.0 MB
  const size_t po4 = (size_t)4 * Bn * Qn * Dn * 2;  // 33.6 MB
  const size_t need8 = base + po8 + lb8;            // 84.94 MB (proven fits)

  hipMemsetAsync(sumV, 0, Bn * Dn * sizeof(float), stream);
  prep_kernel<<<dim3(32, 4, Bn), dim3(32, 8), 0, stream>>>(Kg, Vg, Kh, Vt, sumV);

  if (ws_size >= need8) {
    float* Lb = (float*)(ws + base + po8);
    flash_kernel<8><<<dim3(16, Bn, 8), 256, 0, stream>>>(Qg, Kh, Vt, vl, Po, Lb);
    combine_kernel<8><<<dim3(Qn / 64, Bn), 256, 0, stream>>>(Po, Lb, sumV, vl, Out);
  } else {
    float* Lb = (float*)(ws + base + po4);
    flash_kernel<4><<<dim3(16, Bn, 4), 256, 0, stream>>>(Qg, Kh, Vt, vl, Po, Lb);
    combine_kernel<4><<<dim3(Qn / 64, Bn), 256, 0, stream>>>(Po, Lb, sumV, vl, Out);
  }
}

// Round 8
// 152.657 us; speedup vs baseline: 1.8220x; 1.8220x over previous
//
#include <hip/hip_runtime.h>
#include <hip/hip_bf16.h>
#include <math.h>

// DotProductAttention: B=16, Q=2048, K=2048, D=128, fp32 in/out.
// Query-axis masking: rows q >= valid_lens[b] -> uniform softmax -> mean(V)
// (combine writes those rows exactly from fp32 V column sums).
//
// Round 8: R7's KT=64 tiles (32KB LDS/block) but WITHOUT the forced
// launch_bounds(256,4) — R7's bound made the allocator spill O/qf to scratch
// (VGPR=64, 629MB HBM traffic, 191us). With (256,2) the structure compiles to
// 128 VGPR (proven R5, zero spill) -> 4 waves/SIMD natural occupancy AND
// 4 blocks/CU via the 32KB tile. 32x32x16 MFMA S^T slot-permutation layout
// (verified R5): pi = swap bits 2<->3; S^T C-regs ARE the PV A-fragment.
//
// ws: [0,8K) sumV | Kh 8M (swizzled granules) | Vt 8M (64-key tiles, swizzled)
//     | Po f16 SEG planes | Lb f32.  SEG=8 needs 84.94MB (proven fits).

#define Bn 16
#define Qn 2048
#define Kn 2048
#define Dn 128
#define SCALE 0.08838834764831845f  // 1/sqrt(128)

typedef _Float16 f16;
typedef _Float16 f16x8_t __attribute__((ext_vector_type(8)));
typedef float f32x16_t __attribute__((ext_vector_type(16)));

typedef __attribute__((address_space(1))) const unsigned int glb_u32;
typedef __attribute__((address_space(3))) unsigned int lds_u32;

__device__ __forceinline__ void g2l16(const void* g, void* l) {
  __builtin_amdgcn_global_load_lds((glb_u32*)g, (lds_u32*)l, 16, 0, 0);
}

// ---------------- prep: K->f16 swizzled granules, V->Vt 64-key tiles, colsum
// grid (32, 4, 16) block (32,8).
// Kh key-row k (256B): granule G=d>>3 stored at slot (G&8)|((G&7)^(k&7)).
// Vt tile [b][kb=k/64][d][kk=k%64] (16KB): granule G=kk>>3 (0..7) at slot
// G^(d&7), i.e. element addr ((b*32+kb)*128+d)*64 + slot*8 + (kk&7).

__global__ void __launch_bounds__(256) prep_kernel(
    const float* __restrict__ Kg, const float* __restrict__ Vg,
    f16* __restrict__ Kh, f16* __restrict__ Vt, float* __restrict__ sv) {
  __shared__ float ps[8][32];
  const int b = blockIdx.z;
  const int x = threadIdx.x, y = threadIdx.y;

  // K: 16 key-rows per block, one granule (8 d) per thread, 16B store
  {
    const int lb = (b * 4 + blockIdx.y) * 32 + blockIdx.x;  // 0..2047
    const int t = y * 32 + x;
    const size_t key = (size_t)lb * 16 + (t >> 4);  // global (b*2048+k)
    const int G = t & 15;
    const float* kp = Kg + (key << 7) + G * 8;
    float4 f0 = *(const float4*)kp;
    float4 f1 = *(const float4*)(kp + 4);
    f16x8_t o;
    o[0] = (f16)f0.x; o[1] = (f16)f0.y; o[2] = (f16)f0.z; o[3] = (f16)f0.w;
    o[4] = (f16)f1.x; o[5] = (f16)f1.y; o[6] = (f16)f1.z; o[7] = (f16)f1.w;
    const int gs = (G & 8) | ((G & 7) ^ ((int)key & 7));
    *(f16x8_t*)(Kh + (key << 7) + (gs << 3)) = o;
  }

  // V: 64 keys x 32 d per block; thread owns one Vt granule in-register
  const int k0 = blockIdx.x * 64, d0 = blockIdx.y * 32;
  const int d = d0 + x;
  const float* vp = Vg + ((size_t)b * Kn + k0 + y * 8) * Dn + d;
  float s = 0.f;
  f16x8_t gr;
#pragma unroll
  for (int j = 0; j < 8; j++) {
    float v = vp[(size_t)j * Dn];
    s += v;
    gr[j] = (f16)v;
  }
  {
    const int kb = k0 >> 6;  // 64-key tile index
    const int G = y;         // kk granule 0..7
    const int gs = G ^ (d & 7);
    *(f16x8_t*)(Vt + (((size_t)(b * (Kn / 64) + kb) * 128 + d) << 6) + (gs << 3)) = gr;
  }

  // column sums for the masked fast path
  ps[y][x] = s;
  __syncthreads();
  if (y == 0) {
    float tot = 0.f;
#pragma unroll
    for (int j = 0; j < 8; j++) tot += ps[j][x];
    atomicAdd(&sv[b * Dn + d0 + x], tot);
  }
}

// valid_lens may be stored as int32 or int64. Sniff: odd words all zero -> 64.
__device__ __forceinline__ int load_vl(const int* __restrict__ vlp, int b) {
  bool is64 = true;
#pragma unroll
  for (int i = 1; i < 16; i += 2) is64 = is64 && (vlp[i] == 0);
  return is64 ? vlp[2 * b] : vlp[b];
}

// ---------------- flash: 32x32 MFMA, 32 q/wave, 64-key tiles ----------------
// grid (16, 16, S) block 256.  (256,2): allocator free to use 128 VGPR.

template <int S>
__global__ void __launch_bounds__(256, 2) flash_kernel(
    const float* __restrict__ Qg, const f16* __restrict__ Kh,
    const f16* __restrict__ Vt, const int* __restrict__ vlp,
    f16* __restrict__ Po, float* __restrict__ Lb) {
  const int b = blockIdx.y;
  const int seg = blockIdx.z;
  const int qt = (blockIdx.x * 5 + seg * 3) & 15;  // scatter active tiles
  const int q0 = qt * 128;
  const int vl = load_vl(vlp, b);
  if (q0 >= vl) return;  // uniform per block, before any barrier

  __shared__ __align__(16) f16 Ks[64 * 128];  // 16 KB: 64 keys x 256B rows
  __shared__ __align__(16) f16 Vs[128 * 64];  // 16 KB: 128 d   x 128B rows

  const int tid = threadIdx.x;
  const int wave = tid >> 6, lane = tid & 63;
  const int H = lane >> 5, l5 = lane & 31;
  const int qbase = q0 + wave * 32;
  const bool act = qbase < vl;
  const int q_lane = qbase + l5;
  const float sc = (q_lane >= vl) ? 0.f : SCALE;  // masked row: p=1 -> uniform

  // pi = swap bits 2<->3: A-row slot l5 holds physical key pi(l5) [R5-verified]
  const int krow = (l5 & 0x13) | ((l5 & 4) << 1) | ((l5 & 8) >> 1);
  const int krow7 = krow & 7;

  // Q fragments (B-operand of S^T): lane = q-col l5, k-els d = 16s+8H+j
  f16x8_t qf[8];
  if (act) {
    const float* qp = Qg + ((size_t)b * Qn + q_lane) * Dn + 8 * H;
#pragma unroll
    for (int s = 0; s < 8; s++) {
      float4 f0 = *(const float4*)(qp + 16 * s);
      float4 f1 = *(const float4*)(qp + 16 * s + 4);
      f16x8_t q8;
      q8[0] = (f16)f0.x; q8[1] = (f16)f0.y; q8[2] = (f16)f0.z; q8[3] = (f16)f0.w;
      q8[4] = (f16)f1.x; q8[5] = (f16)f1.y; q8[6] = (f16)f1.z; q8[7] = (f16)f1.w;
      qf[s] = q8;
    }
  }

  f32x16_t O[4];
#pragma unroll
  for (int i = 0; i < 4; i++) O[i] = (f32x16_t)(0.f);
  float l_lane = 0.f;

  const char* KgT = (const char*)Kh + (((size_t)b * Kn + (size_t)seg * (Kn / S)) << 8);
  const char* VgT = (const char*)Vt + ((size_t)(b * (Kn / 64) + seg * (Kn / S) / 64) << 14);

  for (int it = 0; it < (Kn / S) / 64; it++) {
    __syncthreads();  // protect LDS from previous iter's readers
    // stage 32 KB: 8 x 1KB chunks per wave (4 K + 4 V), width-16 DMA
    const char* kg = KgT + (size_t)it * 16384 + wave * 4096 + lane * 16;
    const char* vg = VgT + (size_t)it * 16384 + wave * 4096 + lane * 16;
    f16* kl = Ks + wave * 2048;
    f16* vli = Vs + wave * 2048;
#pragma unroll
    for (int i = 0; i < 4; i++) {
      g2l16(kg + i * 1024, kl + i * 512);
      g2l16(vg + i * 1024, vli + i * 512);
    }
    __syncthreads();

    if (act) {
#pragma unroll
      for (int sub = 0; sub < 2; sub++) {
        // S^T = K.Q^T over keys sub*32..+31
        f32x16_t T = (f32x16_t)(0.f);
        const f16* krp = Ks + ((sub * 32 + krow) << 7);
#pragma unroll
        for (int s = 0; s < 8; s++) {
          const int G = 2 * s + H;
          const int gs = (G & 8) | ((G & 7) ^ krow7);
          f16x8_t kf = *(const f16x8_t*)(krp + (gs << 3));
          T = __builtin_amdgcn_mfma_f32_32x32x16_f16(kf, qf[s], T, 0, 0, 0);
        }

        // p = exp(s); C-regs are the PV A-fragment (key 16(r>>3)+8H+(r&7))
        f16x8_t pf0, pf1;
        float ls = 0.f;
#pragma unroll
        for (int r = 0; r < 8; r++) {
          float p = __expf(T[r] * sc);
          ls += p;
          pf0[r] = (f16)p;
        }
#pragma unroll
        for (int r = 8; r < 16; r++) {
          float p = __expf(T[r] * sc);
          ls += p;
          pf1[r - 8] = (f16)p;
        }
        l_lane += ls;

        // O += P.V : B-frags from swizzled Vs (d-row dt*32+l5, 128B rows)
#pragma unroll
        for (int dt = 0; dt < 4; dt++) {
          const f16* vrp = Vs + ((dt * 32 + l5) << 6);
          const int G0 = sub * 4 + H, G1 = sub * 4 + 2 + H;  // 0..7
          const int gs0 = G0 ^ (l5 & 7);
          const int gs1 = G1 ^ (l5 & 7);
          f16x8_t vf0 = *(const f16x8_t*)(vrp + (gs0 << 3));
          f16x8_t vf1 = *(const f16x8_t*)(vrp + (gs1 << 3));
          O[dt] = __builtin_amdgcn_mfma_f32_32x32x16_f16(pf0, vf0, O[dt], 0, 0, 0);
          O[dt] = __builtin_amdgcn_mfma_f32_32x32x16_f16(pf1, vf1, O[dt], 0, 0, 0);
        }
      }
    }
  }

  if (!act) return;

  // epilogue: unnormalized partials
  l_lane += __shfl_xor(l_lane, 32);
  if (lane < 32) Lb[(size_t)(seg * Bn + b) * Qn + qbase + l5] = l_lane;

  f16* po = Po + ((size_t)(seg * Bn + b) * Qn + qbase) * Dn;
#pragma unroll
  for (int dt = 0; dt < 4; dt++) {
#pragma unroll
    for (int r = 0; r < 16; r++) {
      const int qrow = (r & 3) + 8 * (r >> 2) + 4 * H;  // PV C-layout row
      po[(size_t)qrow * Dn + dt * 32 + l5] = (f16)O[dt][r];
    }
  }
}

// ---------------- combine: out = sum_s O_s / sum_s l_s; masked rows = mean(V)
// grid (32, 16) block 256; 64 q-rows per block, 8 d per thread.

template <int S>
__global__ void __launch_bounds__(256) combine_kernel(
    const f16* __restrict__ Po, const float* __restrict__ Lb,
    const float* __restrict__ sv, const int* __restrict__ vlp,
    float* __restrict__ Out) {
  const int b = blockIdx.y, q0 = blockIdx.x * 64;
  const int vl = load_vl(vlp, b);
  const int tid = threadIdx.x;

  __shared__ float linv[64];
  if (tid < 64) {
    float s = 0.f;
#pragma unroll
    for (int sg = 0; sg < S; sg++) s += Lb[(size_t)(sg * Bn + b) * Qn + q0 + tid];
    linv[tid] = 1.0f / s;
  }
  __syncthreads();

  const int row16 = tid >> 4;     // 0..15
  const int d8 = (tid & 15) * 8;  // 0..120
  const float invK = 1.0f / (float)Kn;
  float mv[8];
#pragma unroll
  for (int j = 0; j < 8; j++) mv[j] = sv[b * Dn + d8 + j] * invK;

#pragma unroll
  for (int pass = 0; pass < 4; pass++) {
    const int row = pass * 16 + row16;
    const int q = q0 + row;
    float acc[8];
    if (q >= vl) {
#pragma unroll
      for (int j = 0; j < 8; j++) acc[j] = mv[j];  // fp32-exact uniform result
    } else {
#pragma unroll
      for (int j = 0; j < 8; j++) acc[j] = 0.f;
#pragma unroll
      for (int sg = 0; sg < S; sg++) {
        f16x8_t v = *(const f16x8_t*)(Po + ((size_t)(sg * Bn + b) * Qn + q) * Dn + d8);
#pragma unroll
        for (int j = 0; j < 8; j++) acc[j] += (float)v[j];
      }
      const float li = linv[row];
#pragma unroll
      for (int j = 0; j < 8; j++) acc[j] *= li;
    }
    float4 o0 = make_float4(acc[0], acc[1], acc[2], acc[3]);
    float4 o1 = make_float4(acc[4], acc[5], acc[6], acc[7]);
    float* op = Out + ((size_t)b * Qn + q) * Dn + d8;
    *(float4*)op = o0;
    *(float4*)(op + 4) = o1;
  }
}

// ---------------- launch ----------------

extern "C" void kernel_launch(void* const* d_in, const int* in_sizes, int n_in,
                              void* d_out, int out_size, void* d_ws, size_t ws_size,
                              hipStream_t stream) {
  const float* Qg = (const float*)d_in[0];
  const float* Kg = (const float*)d_in[1];
  const float* Vg = (const float*)d_in[2];
  const int* vl = (const int*)d_in[3];
  float* Out = (float*)d_out;

  char* ws = (char*)d_ws;
  float* sumV = (float*)ws;                                // 8 KB
  f16* Kh = (f16*)(ws + 8192);                             // 8 MB
  f16* Vt = (f16*)(ws + 8192 + (size_t)Bn * Kn * Dn * 2);  // 8 MB
  const size_t base = 8192 + 2 * (size_t)Bn * Kn * Dn * 2;
  f16* Po = (f16*)(ws + base);

  const size_t po8 = (size_t)8 * Bn * Qn * Dn * 2;  // 67.1 MB
  const size_t lb8 = (size_t)8 * Bn * Qn * 4;       // 1.0 MB
  const size_t po4 = (size_t)4 * Bn * Qn * Dn * 2;  // 33.6 MB
  const size_t need8 = base + po8 + lb8;            // 84.94 MB (proven fits)

  hipMemsetAsync(sumV, 0, Bn * Dn * sizeof(float), stream);
  prep_kernel<<<dim3(32, 4, Bn), dim3(32, 8), 0, stream>>>(Kg, Vg, Kh, Vt, sumV);

  if (ws_size >= need8) {
    float* Lb = (float*)(ws + base + po8);
    flash_kernel<8><<<dim3(16, Bn, 8), 256, 0, stream>>>(Qg, Kh, Vt, vl, Po, Lb);
    combine_kernel<8><<<dim3(Qn / 64, Bn), 256, 0, stream>>>(Po, Lb, sumV, vl, Out);
  } else {
    float* Lb = (float*)(ws + base + po4);
    flash_kernel<4><<<dim3(16, Bn, 4), 256, 0, stream>>>(Qg, Kh, Vt, vl, Po, Lb);
    combine_kernel<4><<<dim3(Qn / 64, Bn), 256, 0, stream>>>(Po, Lb, sumV, vl, Out);
  }
}

// Round 9
// 144.319 us; speedup vs baseline: 1.9273x; 1.0578x over previous
//
#include <hip/hip_runtime.h>
#include <hip/hip_bf16.h>
#include <math.h>

// DotProductAttention: B=16, Q=2048, K=2048, D=128, fp32 in/out.
// Query-axis masking: rows q >= valid_lens[b] -> uniform softmax -> mean(V)
// (combine writes those rows exactly from fp32 V column sums).
//
// Round 9: LOOP INVERSION. R5==R8 (55us) proved the K-loop structure
// (re-stage 64-128 keys per iter, barrier drain each iter, K/V re-read 8.5x)
// is the floor regardless of tile size / residency. New flash_q: each block
// owns one (b, seg-of-128-keys) slice, stages K+V (64KB) ONCE, one barrier,
// then a barrier-free q-loop over active q-tiles (LDS is read-only).
// SEG=16, J=2 interleaved q-blocks per slice (same-XCD by construction).
// All MFMA fragment/slot formulas verbatim from R5 (verified on HW):
// 32x32x16, S^T slot-permutation pi = swap bits 2<->3.
// Needs ws >= ~161.5MB; falls back to R8's exact proven kernel otherwise.
//
// ws primary: sumV 8K | Kh 8M | Vt 8M (128-key tiles) | Qh 8M | Po 16 planes
//             f16 134M | Lb 2M.
// ws fallback(R8): sumV 8K | Kh 8M | Vt 8M (64-key tiles) | Po 8 planes | Lb.

#define Bn 16
#define Qn 2048
#define Kn 2048
#define Dn 128
#define SCALE 0.08838834764831845f  // 1/sqrt(128)

typedef _Float16 f16;
typedef _Float16 f16x8_t __attribute__((ext_vector_type(8)));
typedef float f32x16_t __attribute__((ext_vector_type(16)));

typedef __attribute__((address_space(1))) const unsigned int glb_u32;
typedef __attribute__((address_space(3))) unsigned int lds_u32;

__device__ __forceinline__ void g2l16(const void* g, void* l) {
  __builtin_amdgcn_global_load_lds((glb_u32*)g, (lds_u32*)l, 16, 0, 0);
}

// ---------------- prep: K->f16 swizzled rows, V->Vt tiles, opt Q->f16, colsum
// grid (32, 4, 16) block (32,8).
// Kh key-row k (256B): granule G=d>>3 at slot (G&8)|((G&7)^(k&7))  [verified]
// VT=128: Vt tile [b][k/128][d][kk] 32KB, G=kk>>3 at (G&8)|((G&7)^(d&7)) [R6]
// VT=64 : Vt tile [b][k/64][d][kk] 16KB, G=kk>>3 at G^(d&7)             [R8]
// Qh (optional): plain row-major f16.

template <int VT>
__global__ void __launch_bounds__(256) prep_kernel(
    const float* __restrict__ Qg, const float* __restrict__ Kg,
    const float* __restrict__ Vg, f16* __restrict__ Qh, f16* __restrict__ Kh,
    f16* __restrict__ Vt, float* __restrict__ sv) {
  __shared__ float ps[8][32];
  const int b = blockIdx.z;
  const int x = threadIdx.x, y = threadIdx.y;

  // K (and optionally Q): 16 rows per block, one granule (8 d) per thread
  {
    const int lb = (b * 4 + blockIdx.y) * 32 + blockIdx.x;  // 0..2047
    const int t = y * 32 + x;
    const size_t key = (size_t)lb * 16 + (t >> 4);  // global (b*2048+k)
    const int G = t & 15;
    const float* kp = Kg + (key << 7) + G * 8;
    float4 f0 = *(const float4*)kp;
    float4 f1 = *(const float4*)(kp + 4);
    f16x8_t o;
    o[0] = (f16)f0.x; o[1] = (f16)f0.y; o[2] = (f16)f0.z; o[3] = (f16)f0.w;
    o[4] = (f16)f1.x; o[5] = (f16)f1.y; o[6] = (f16)f1.z; o[7] = (f16)f1.w;
    const int gs = (G & 8) | ((G & 7) ^ ((int)key & 7));
    *(f16x8_t*)(Kh + (key << 7) + (gs << 3)) = o;
    if (Qh != nullptr) {
      const float* qp = Qg + (key << 7) + G * 8;
      float4 q0 = *(const float4*)qp;
      float4 q1 = *(const float4*)(qp + 4);
      f16x8_t oq;
      oq[0] = (f16)q0.x; oq[1] = (f16)q0.y; oq[2] = (f16)q0.z; oq[3] = (f16)q0.w;
      oq[4] = (f16)q1.x; oq[5] = (f16)q1.y; oq[6] = (f16)q1.z; oq[7] = (f16)q1.w;
      *(f16x8_t*)(Qh + (key << 7) + G * 8) = oq;  // plain row-major
    }
  }

  // V: 64 keys x 32 d per block; thread owns one Vt granule in-register
  const int k0 = blockIdx.x * 64, d0 = blockIdx.y * 32;
  const int d = d0 + x;
  const float* vp = Vg + ((size_t)b * Kn + k0 + y * 8) * Dn + d;
  float s = 0.f;
  f16x8_t gr;
#pragma unroll
  for (int j = 0; j < 8; j++) {
    float v = vp[(size_t)j * Dn];
    s += v;
    gr[j] = (f16)v;
  }
  if (VT == 128) {
    const int kb = k0 >> 7;
    const int G = ((k0 & 64) >> 3) + y;  // kk granule 0..15
    const int gs = (G & 8) | ((G & 7) ^ (d & 7));
    *(f16x8_t*)(Vt + (((size_t)(b * (Kn / 128) + kb) * 128 + d) << 7) + (gs << 3)) = gr;
  } else {
    const int kb = k0 >> 6;
    const int G = y;  // kk granule 0..7
    const int gs = G ^ (d & 7);
    *(f16x8_t*)(Vt + (((size_t)(b * (Kn / 64) + kb) * 128 + d) << 6) + (gs << 3)) = gr;
  }

  // column sums for the masked fast path
  ps[y][x] = s;
  __syncthreads();
  if (y == 0) {
    float tot = 0.f;
#pragma unroll
    for (int j = 0; j < 8; j++) tot += ps[j][x];
    atomicAdd(&sv[b * Dn + d0 + x], tot);
  }
}

// valid_lens may be stored as int32 or int64. Sniff: odd words all zero -> 64.
__device__ __forceinline__ int load_vl(const int* __restrict__ vlp, int b) {
  bool is64 = true;
#pragma unroll
  for (int i = 1; i < 16; i += 2) is64 = is64 && (vlp[i] == 0);
  return is64 ? vlp[2 * b] : vlp[b];
}

// ---------------- flash_q: stage-once, q-loop-outer. SEG=16, 128-key slices.
// grid (J*16, Bn) block 256.  x = seg + 16*j -> both j-blocks of a slice land
// on the same XCD (lin%8 == seg%8) for K/V L2 reuse.

template <int J>
__global__ void __launch_bounds__(256, 2) flash_q(
    const f16* __restrict__ Qh, const f16* __restrict__ Kh,
    const f16* __restrict__ Vt, const int* __restrict__ vlp,
    f16* __restrict__ Po, float* __restrict__ Lb) {
  const int b = blockIdx.y;
  const int seg = blockIdx.x & 15;
  const int j = blockIdx.x >> 4;
  const int vl = load_vl(vlp, b);
  const int nq = (vl + 127) >> 7;  // active q-tiles
  if (nq == 0) return;

  __shared__ __align__(16) f16 Ks[128 * 128];  // 32 KB: 128 keys x 256B rows
  __shared__ __align__(16) f16 Vs[128 * 128];  // 32 KB: 128 d    x 256B rows

  const int tid = threadIdx.x;
  const int wave = tid >> 6, lane = tid & 63;
  const int H = lane >> 5, l5 = lane & 31;

  // stage 64 KB ONCE: 16 x 1KB chunks per wave (8 K + 8 V), width-16 DMA
  {
    const char* kg = (const char*)Kh + (((size_t)b * Kn + seg * 128) << 8) +
                     wave * 8192 + lane * 16;
    const char* vg = (const char*)Vt + ((size_t)(b * (Kn / 128) + seg) << 15) +
                     wave * 8192 + lane * 16;
    f16* kl = Ks + wave * 4096;
    f16* vli = Vs + wave * 4096;
#pragma unroll
    for (int i = 0; i < 8; i++) {
      g2l16(kg + i * 1024, kl + i * 512);
      g2l16(vg + i * 1024, vli + i * 512);
    }
  }
  __syncthreads();  // ONLY barrier: LDS is read-only afterwards

  // pi = swap bits 2<->3: A-row slot l5 holds physical key pi(l5) [R5-verified]
  const int krow = (l5 & 0x13) | ((l5 & 4) << 1) | ((l5 & 8) >> 1);
  const int krow7 = krow & 7;

  for (int qt = j; qt < nq; qt += J) {
    const int q0 = qt << 7;
    const int qbase = q0 + wave * 32;
    if (qbase >= vl) continue;  // no barriers: waves free to skip
    const int q_lane = qbase + l5;
    const float sc = (q_lane >= vl) ? 0.f : SCALE;  // masked row: p=1

    // Q fragment (B-operand of S^T): lane = q-col l5, k-els d = 16s+8H+jj
    f16x8_t qf[8];
    {
      const f16* qp = Qh + ((size_t)b * Qn + q_lane) * Dn + 8 * H;
#pragma unroll
      for (int s = 0; s < 8; s++) qf[s] = *(const f16x8_t*)(qp + 16 * s);
    }

    f32x16_t O[4];
#pragma unroll
    for (int i = 0; i < 4; i++) O[i] = (f32x16_t)(0.f);
    float l_lane = 0.f;

#pragma unroll
    for (int sub = 0; sub < 4; sub++) {
      // S^T = K.Q^T over keys sub*32..+31   [formulas verbatim from R5]
      f32x16_t T = (f32x16_t)(0.f);
      const f16* krp = Ks + ((sub * 32 + krow) << 7);
#pragma unroll
      for (int s = 0; s < 8; s++) {
        const int G = 2 * s + H;
        const int gs = (G & 8) | ((G & 7) ^ krow7);
        f16x8_t kf = *(const f16x8_t*)(krp + (gs << 3));
        T = __builtin_amdgcn_mfma_f32_32x32x16_f16(kf, qf[s], T, 0, 0, 0);
      }

      // p = exp(s); C-regs are the PV A-fragment (key 16(r>>3)+8H+(r&7))
      f16x8_t pf0, pf1;
      float ls = 0.f;
#pragma unroll
      for (int r = 0; r < 8; r++) {
        float p = __expf(T[r] * sc);
        ls += p;
        pf0[r] = (f16)p;
      }
#pragma unroll
      for (int r = 8; r < 16; r++) {
        float p = __expf(T[r] * sc);
        ls += p;
        pf1[r - 8] = (f16)p;
      }
      l_lane += ls;

      // O += P.V : B-frags from swizzled Vs (d-row dt*32+l5, 256B rows)
#pragma unroll
      for (int dt = 0; dt < 4; dt++) {
        const f16* vrp = Vs + ((dt * 32 + l5) << 7);
        const int G0 = sub * 4 + H, G1 = sub * 4 + 2 + H;  // 0..15
        const int gs0 = (G0 & 8) | ((G0 & 7) ^ (l5 & 7));
        const int gs1 = (G1 & 8) | ((G1 & 7) ^ (l5 & 7));
        f16x8_t vf0 = *(const f16x8_t*)(vrp + (gs0 << 3));
        f16x8_t vf1 = *(const f16x8_t*)(vrp + (gs1 << 3));
        O[dt] = __builtin_amdgcn_mfma_f32_32x32x16_f16(pf0, vf0, O[dt], 0, 0, 0);
        O[dt] = __builtin_amdgcn_mfma_f32_32x32x16_f16(pf1, vf1, O[dt], 0, 0, 0);
      }
    }

    // epilogue for this q-tile: unnormalized partials
    float ll = l_lane + __shfl_xor(l_lane, 32);
    if (lane < 32) Lb[(size_t)(seg * Bn + b) * Qn + qbase + l5] = ll;

    f16* po = Po + ((size_t)(seg * Bn + b) * Qn + qbase) * Dn;
#pragma unroll
    for (int dt = 0; dt < 4; dt++) {
#pragma unroll
      for (int r = 0; r < 16; r++) {
        const int qrow = (r & 3) + 8 * (r >> 2) + 4 * H;  // PV C-layout row
        po[(size_t)qrow * Dn + dt * 32 + l5] = (f16)O[dt][r];
      }
    }
  }
}

// ---------------- flash_seq: R8's proven kernel (fallback if ws too small) --
// grid (16, 16, S) block 256.

template <int S>
__global__ void __launch_bounds__(256, 2) flash_seq(
    const float* __restrict__ Qg, const f16* __restrict__ Kh,
    const f16* __restrict__ Vt, const int* __restrict__ vlp,
    f16* __restrict__ Po, float* __restrict__ Lb) {
  const int b = blockIdx.y;
  const int seg = blockIdx.z;
  const int qt = (blockIdx.x * 5 + seg * 3) & 15;
  const int q0 = qt * 128;
  const int vl = load_vl(vlp, b);
  if (q0 >= vl) return;

  __shared__ __align__(16) f16 Ks[64 * 128];
  __shared__ __align__(16) f16 Vs[128 * 64];

  const int tid = threadIdx.x;
  const int wave = tid >> 6, lane = tid & 63;
  const int H = lane >> 5, l5 = lane & 31;
  const int qbase = q0 + wave * 32;
  const bool act = qbase < vl;
  const int q_lane = qbase + l5;
  const float sc = (q_lane >= vl) ? 0.f : SCALE;

  const int krow = (l5 & 0x13) | ((l5 & 4) << 1) | ((l5 & 8) >> 1);
  const int krow7 = krow & 7;

  f16x8_t qf[8];
  if (act) {
    const float* qp = Qg + ((size_t)b * Qn + q_lane) * Dn + 8 * H;
#pragma unroll
    for (int s = 0; s < 8; s++) {
      float4 f0 = *(const float4*)(qp + 16 * s);
      float4 f1 = *(const float4*)(qp + 16 * s + 4);
      f16x8_t q8;
      q8[0] = (f16)f0.x; q8[1] = (f16)f0.y; q8[2] = (f16)f0.z; q8[3] = (f16)f0.w;
      q8[4] = (f16)f1.x; q8[5] = (f16)f1.y; q8[6] = (f16)f1.z; q8[7] = (f16)f1.w;
      qf[s] = q8;
    }
  }

  f32x16_t O[4];
#pragma unroll
  for (int i = 0; i < 4; i++) O[i] = (f32x16_t)(0.f);
  float l_lane = 0.f;

  const char* KgT = (const char*)Kh + (((size_t)b * Kn + (size_t)seg * (Kn / S)) << 8);
  const char* VgT = (const char*)Vt + ((size_t)(b * (Kn / 64) + seg * (Kn / S) / 64) << 14);

  for (int it = 0; it < (Kn / S) / 64; it++) {
    __syncthreads();
    const char* kg = KgT + (size_t)it * 16384 + wave * 4096 + lane * 16;
    const char* vg = VgT + (size_t)it * 16384 + wave * 4096 + lane * 16;
    f16* kl = Ks + wave * 2048;
    f16* vli = Vs + wave * 2048;
#pragma unroll
    for (int i = 0; i < 4; i++) {
      g2l16(kg + i * 1024, kl + i * 512);
      g2l16(vg + i * 1024, vli + i * 512);
    }
    __syncthreads();

    if (act) {
#pragma unroll
      for (int sub = 0; sub < 2; sub++) {
        f32x16_t T = (f32x16_t)(0.f);
        const f16* krp = Ks + ((sub * 32 + krow) << 7);
#pragma unroll
        for (int s = 0; s < 8; s++) {
          const int G = 2 * s + H;
          const int gs = (G & 8) | ((G & 7) ^ krow7);
          f16x8_t kf = *(const f16x8_t*)(krp + (gs << 3));
          T = __builtin_amdgcn_mfma_f32_32x32x16_f16(kf, qf[s], T, 0, 0, 0);
        }
        f16x8_t pf0, pf1;
        float ls = 0.f;
#pragma unroll
        for (int r = 0; r < 8; r++) {
          float p = __expf(T[r] * sc);
          ls += p;
          pf0[r] = (f16)p;
        }
#pragma unroll
        for (int r = 8; r < 16; r++) {
          float p = __expf(T[r] * sc);
          ls += p;
          pf1[r - 8] = (f16)p;
        }
        l_lane += ls;
#pragma unroll
        for (int dt = 0; dt < 4; dt++) {
          const f16* vrp = Vs + ((dt * 32 + l5) << 6);
          const int G0 = sub * 4 + H, G1 = sub * 4 + 2 + H;
          const int gs0 = G0 ^ (l5 & 7);
          const int gs1 = G1 ^ (l5 & 7);
          f16x8_t vf0 = *(const f16x8_t*)(vrp + (gs0 << 3));
          f16x8_t vf1 = *(const f16x8_t*)(vrp + (gs1 << 3));
          O[dt] = __builtin_amdgcn_mfma_f32_32x32x16_f16(pf0, vf0, O[dt], 0, 0, 0);
          O[dt] = __builtin_amdgcn_mfma_f32_32x32x16_f16(pf1, vf1, O[dt], 0, 0, 0);
        }
      }
    }
  }

  if (!act) return;

  l_lane += __shfl_xor(l_lane, 32);
  if (lane < 32) Lb[(size_t)(seg * Bn + b) * Qn + qbase + l5] = l_lane;

  f16* po = Po + ((size_t)(seg * Bn + b) * Qn + qbase) * Dn;
#pragma unroll
  for (int dt = 0; dt < 4; dt++) {
#pragma unroll
    for (int r = 0; r < 16; r++) {
      const int qrow = (r & 3) + 8 * (r >> 2) + 4 * H;
      po[(size_t)qrow * Dn + dt * 32 + l5] = (f16)O[dt][r];
    }
  }
}

// ---------------- combine: out = sum_s O_s / sum_s l_s; masked rows = mean(V)
// grid (32, 16) block 256; 64 q-rows per block, 8 d per thread.

template <int S>
__global__ void __launch_bounds__(256) combine_kernel(
    const f16* __restrict__ Po, const float* __restrict__ Lb,
    const float* __restrict__ sv, const int* __restrict__ vlp,
    float* __restrict__ Out) {
  const int b = blockIdx.y, q0 = blockIdx.x * 64;
  const int vl = load_vl(vlp, b);
  const int tid = threadIdx.x;

  __shared__ float linv[64];
  if (tid < 64) {
    float s = 0.f;
#pragma unroll
    for (int sg = 0; sg < S; sg++) s += Lb[(size_t)(sg * Bn + b) * Qn + q0 + tid];
    linv[tid] = 1.0f / s;
  }
  __syncthreads();

  const int row16 = tid >> 4;     // 0..15
  const int d8 = (tid & 15) * 8;  // 0..120
  const float invK = 1.0f / (float)Kn;
  float mv[8];
#pragma unroll
  for (int j = 0; j < 8; j++) mv[j] = sv[b * Dn + d8 + j] * invK;

#pragma unroll
  for (int pass = 0; pass < 4; pass++) {
    const int row = pass * 16 + row16;
    const int q = q0 + row;
    float acc[8];
    if (q >= vl) {
#pragma unroll
      for (int j = 0; j < 8; j++) acc[j] = mv[j];
    } else {
#pragma unroll
      for (int j = 0; j < 8; j++) acc[j] = 0.f;
#pragma unroll
      for (int sg = 0; sg < S; sg++) {
        f16x8_t v = *(const f16x8_t*)(Po + ((size_t)(sg * Bn + b) * Qn + q) * Dn + d8);
#pragma unroll
        for (int j = 0; j < 8; j++) acc[j] += (float)v[j];
      }
      const float li = linv[row];
#pragma unroll
      for (int j = 0; j < 8; j++) acc[j] *= li;
    }
    float4 o0 = make_float4(acc[0], acc[1], acc[2], acc[3]);
    float4 o1 = make_float4(acc[4], acc[5], acc[6], acc[7]);
    float* op = Out + ((size_t)b * Qn + q) * Dn + d8;
    *(float4*)op = o0;
    *(float4*)(op + 4) = o1;
  }
}

// ---------------- launch ----------------

extern "C" void kernel_launch(void* const* d_in, const int* in_sizes, int n_in,
                              void* d_out, int out_size, void* d_ws, size_t ws_size,
                              hipStream_t stream) {
  const float* Qg = (const float*)d_in[0];
  const float* Kg = (const float*)d_in[1];
  const float* Vg = (const float*)d_in[2];
  const int* vl = (const int*)d_in[3];
  float* Out = (float*)d_out;

  char* ws = (char*)d_ws;
  const size_t kv = (size_t)Bn * Kn * Dn * 2;  // 8.39 MB
  float* sumV = (float*)ws;                    // 8 KB
  f16* Kh = (f16*)(ws + 8192);
  f16* Vt = (f16*)(ws + 8192 + kv);

  const size_t plane = (size_t)Bn * Qn * Dn * 2;     // 8.39 MB
  const size_t lplane = (size_t)Bn * Qn * 4;         // 128 KB
  const size_t need16 = 8192 + 3 * kv + 16 * plane + 16 * lplane;  // ~161.6 MB
  const size_t base8 = 8192 + 2 * kv;
  const size_t need8 = base8 + 8 * plane + 8 * lplane;  // 84.94 MB (proven)

  hipMemsetAsync(sumV, 0, Bn * Dn * sizeof(float), stream);

  if (ws_size >= need16) {
    // primary: stage-once q-loop flash, SEG=16, J=2
    f16* Qh = (f16*)(ws + 8192 + 2 * kv);
    f16* Po = (f16*)(ws + 8192 + 3 * kv);
    float* Lb = (float*)(ws + 8192 + 3 * kv + 16 * plane);
    prep_kernel<128><<<dim3(32, 4, Bn), dim3(32, 8), 0, stream>>>(
        Qg, Kg, Vg, Qh, Kh, Vt, sumV);
    flash_q<2><<<dim3(32, Bn), 256, 0, stream>>>(Qh, Kh, Vt, vl, Po, Lb);
    combine_kernel<16><<<dim3(Qn / 64, Bn), 256, 0, stream>>>(Po, Lb, sumV, vl, Out);
  } else if (ws_size >= need8) {
    // fallback: R8 exact (proven 56us flash)
    f16* Po = (f16*)(ws + base8);
    float* Lb = (float*)(ws + base8 + 8 * plane);
    prep_kernel<64><<<dim3(32, 4, Bn), dim3(32, 8), 0, stream>>>(
        Qg, Kg, Vg, (f16*)nullptr, Kh, Vt, sumV);
    flash_seq<8><<<dim3(16, Bn, 8), 256, 0, stream>>>(Qg, Kh, Vt, vl, Po, Lb);
    combine_kernel<8><<<dim3(Qn / 64, Bn), 256, 0, stream>>>(Po, Lb, sumV, vl, Out);
  } else {
    // minimal fallback: SEG=4
    f16* Po = (f16*)(ws + base8);
    float* Lb = (float*)(ws + base8 + 4 * plane);
    prep_kernel<64><<<dim3(32, 4, Bn), dim3(32, 8), 0, stream>>>(
        Qg, Kg, Vg, (f16*)nullptr, Kh, Vt, sumV);
    flash_seq<4><<<dim3(16, Bn, 4), 256, 0, stream>>>(Qg, Kh, Vt, vl, Po, Lb);
    combine_kernel<4><<<dim3(Qn / 64, Bn), 256, 0, stream>>>(Po, Lb, sumV, vl, Out);
  }
}